// Round 6
// baseline (1188.748 us; speedup 1.0000x reference)
//
#include <hip/hip_runtime.h>
#include <math.h>

#define ITERS 30

// ws float offsets. ws[0..1023] ints = barrier counters (memset each launch).
#define PEND0f 1024      // [b][s][m] iter-0 exact LSE partials: 8*32*512
#define GACCf  132096    // [buf3][b][m] atomic sum accumulators: 3*8*512
#define BPARTf 144384    // per-block epilogue partials: 256*8

#define LN2f    0.69314718055994530942f
#define K2c     2.40449173481494868463f   // 1/(0.6*ln2)
#define KCc     144.269504088896340736f   // 100/ln2
#define RKCc    0.0069314718055994530942f // ln2/100
#define CNEGc  -0.0067955605937249540f    // -eps*damping*ln2, damping=0.5/0.51
#define IRHOL2c 2.88539008177792681472f   // 1/(0.5*ln2)

__device__ __forceinline__ float fexp2(float x){ return __builtin_amdgcn_exp2f(x); }
__device__ __forceinline__ float flog2(float x){ return __builtin_amdgcn_logf(x); }
__device__ __forceinline__ float fsq(float x){ return __builtin_amdgcn_sqrtf(x); }

__device__ __forceinline__ float wave_max(float v){
  #pragma unroll
  for (int off = 1; off < 64; off <<= 1) v = fmaxf(v, __shfl_xor(v, off));
  return v;
}
__device__ __forceinline__ float wave_sum(float v){
  #pragma unroll
  for (int off = 1; off < 64; off <<= 1) v += __shfl_xor(v, off);
  return v;
}

// Arrival: ACQ_REL RMW (proven R2/R5). Poll: RELAXED RMW -- agent-atomic, so
// always coherence-point-fresh (R3's stale-poll bug was a plain relaxed LOAD),
// and emits NO per-poll L2 invalidate (R5's 720MB FETCH storm). One ACQUIRE
// at exit invalidates caches exactly once before partner-data reads.
__device__ __forceinline__ void bar_sync(int* c, int target){
  __syncthreads();
  if (threadIdx.x == 0){
    __hip_atomic_fetch_add(c, 1, __ATOMIC_ACQ_REL, __HIP_MEMORY_SCOPE_AGENT);
    int spins = 0;
    while (__hip_atomic_fetch_add(c, 0, __ATOMIC_RELAXED, __HIP_MEMORY_SCOPE_AGENT) < target){
      if (spins < 4) __builtin_amdgcn_s_sleep(2);
      else           __builtin_amdgcn_s_sleep(32);
      if (++spins > (1 << 20)) break;   // fail visibly, never hang
    }
    (void)__hip_atomic_load(c, __ATOMIC_ACQUIRE, __HIP_MEMORY_SCOPE_AGENT);
  }
  __syncthreads();
}

// Block bb: batch b = bb&7 (XCD co-location heuristic), n-strip s = bb>>3
// (rows n = s*128 + w*8 + r). Lane l, slot k -> m = k*64+l.
// nK[r][k] = -KC * 2^(K2*d(n,m)) cached in 64 VGPRs.
__global__ __launch_bounds__(1024, 4) void k_sink(const float* __restrict__ A,
                                                  const float* __restrict__ pts,
                                                  float* __restrict__ ws,
                                                  float* __restrict__ out){
  __shared__ float2 pms[512 * 17];   // [m][wave] merge buffer (float2 or float view)
  __shared__ float g_lds[512];
  __shared__ float red[96];
  float* pmsf = (float*)pms;
  const int tid = threadIdx.x, w = tid >> 6, l = tid & 63;
  const int bb = blockIdx.x, b = bb & 7, s = bb >> 3;
  int* cnt  = (int*)ws;
  int* cbat = cnt + b * 64;              // slots 0..30 per batch
  float* gacc = ws + GACCf;              // [buf][b][m]

  float nK[64], laK[8], P[8], G2[8], Lf[8], shg[8];

  // ---- prologue: cost tile + log-mass; zero this block's GACC slices
  {
    const float2* p2 = (const float2*)(pts + b*1024);
    float px[8], py[8];
    #pragma unroll
    for (int k = 0; k < 8; ++k){
      float2 pv = p2[k*64 + l];
      px[k] = pv.x * (1.f/512.f);
      py[k] = pv.y * (1.f/512.f);
    }
    #pragma unroll
    for (int r = 0; r < 8; ++r){
      int n = s*128 + w*8 + r;
      float xn = (float)((n & 63) + 1) * (1.f/64.f);
      float yn = (float)((n >> 6) + 1) * (1.f/64.f);
      laK[r] = flog2(A[b*4096 + n] + 1e-20f) + KCc;
      P[r]   = laK[r];
      #pragma unroll
      for (int k = 0; k < 8; ++k){
        float dx = xn - px[k], dy = yn - py[k];
        float d2 = __builtin_fmaf(dy, dy, __builtin_fmaf(dx, dx, 1e-12f));
        nK[r*8 + k] = -KCc * fexp2(fsq(d2) * K2c);
      }
    }
    if (tid < 48){                        // zero GACC[0..2][b][s*16..s*16+15]
      int buf = tid >> 4, idx = tid & 15;
      gacc[buf*4096 + b*512 + s*16 + idx] = 0.f;
    }
  }

  // ---- 30 x { g partials -> barrier -> combine -> f-update }
  #pragma unroll 1
  for (int it = 0; it < ITERS; ++it){
    if (it == 0){
      // EXACT path (bootstrap shg): (M,S) LDS merge, LSE per column to PEND0
      #pragma unroll
      for (int k = 0; k < 8; ++k){
        float y[8], pm = -INFINITY;
        #pragma unroll
        for (int r = 0; r < 8; ++r){ y[r] = P[r] + nK[r*8 + k]; pm = fmaxf(pm, y[r]); }
        float ps = 0.f;
        #pragma unroll
        for (int r = 0; r < 8; ++r) ps += fexp2(y[r] - pm);
        pms[(k*64 + l)*17 + w] = make_float2(pm, ps);
      }
      __syncthreads();
      if (tid < 512){
        float2 v[16]; float M = -INFINITY;
        #pragma unroll
        for (int q = 0; q < 16; ++q){ v[q] = pms[tid*17 + q]; M = fmaxf(M, v[q].x); }
        float S = 0.f;
        #pragma unroll
        for (int q = 0; q < 16; ++q) S += v[q].y * fexp2(v[q].x - M);
        (ws + PEND0f)[(b*32 + s)*512 + tid] = M + flog2(S);
      }
      bar_sync(cbat + 0, 32);
      // redundant combine of 32 LSE partials (once only) -> Lg in g_lds
      {
        int m  = w*32 + (l & 31);
        int s0 = (l >> 5) * 16;
        const float* basep = ws + PEND0f + (b*32 + s0)*512 + m;
        float M = -INFINITY, S = 0.f;
        #pragma unroll
        for (int c = 0; c < 2; ++c){
          float Lr[8], cm = -INFINITY;
          #pragma unroll
          for (int j = 0; j < 8; ++j){ Lr[j] = basep[(c*8 + j)*512]; cm = fmaxf(cm, Lr[j]); }
          float Mn = fmaxf(M, cm), cs = 0.f;
          #pragma unroll
          for (int j = 0; j < 8; ++j) cs += fexp2(Lr[j] - Mn);
          S = __builtin_fmaf(S, fexp2(M - Mn), cs);
          M = Mn;
        }
        float Mo = __shfl_xor(M, 32), So = __shfl_xor(S, 32);
        float Mn = fmaxf(M, Mo);
        float Sn = __builtin_fmaf(S, fexp2(M - Mn), So * fexp2(Mo - Mn));
        if (!(l & 32)) g_lds[m] = Mn + flog2(Sn);     // Lg (pre-CNEG LSE)
      }
      __syncthreads();
      #pragma unroll
      for (int k = 0; k < 8; ++k){
        float Lg = g_lds[k*64 + l];
        shg[k] = Lg;
        G2[k]  = __builtin_fmaf(CNEGc * Lg, KCc, KCc);
      }
      // f-update, exact wave max (sets Lf)
      #pragma unroll
      for (int r = 0; r < 8; ++r){
        float y[8], cm = -INFINITY;
        #pragma unroll
        for (int k = 0; k < 8; ++k){ y[k] = G2[k] + nK[r*8 + k]; cm = fmaxf(cm, y[k]); }
        float M = wave_max(cm);
        float sv = 0.f;
        #pragma unroll
        for (int k = 0; k < 8; ++k) sv += fexp2(y[k] - M);
        float L = M + flog2(wave_sum(sv));
        Lf[r] = L;
        P[r]  = __builtin_fmaf(CNEGc * L, KCc, laK[r]);
      }
    } else {
      // FAST path: shifted plain sums, atomicAdd combine (2KB exchange)
      #pragma unroll
      for (int k = 0; k < 8; ++k){
        float sh = shg[k], sv = 0.f;
        #pragma unroll
        for (int r = 0; r < 8; ++r) sv += fexp2(P[r] + nK[r*8 + k] - sh);
        pmsf[(k*64 + l)*17 + w] = sv;
      }
      __syncthreads();
      if (tid < 512){
        float cb = 0.f;
        #pragma unroll
        for (int q = 0; q < 16; ++q) cb += pmsf[tid*17 + q];
        __hip_atomic_fetch_add(&gacc[(it % 3)*4096 + b*512 + tid], cb,
                               __ATOMIC_RELAXED, __HIP_MEMORY_SCOPE_AGENT);
      }
      bar_sync(cbat + it, 32);
      #pragma unroll
      for (int k = 0; k < 8; ++k){
        float S  = gacc[(it % 3)*4096 + b*512 + k*64 + l];
        float Lg = shg[k] + flog2(S);
        shg[k] = Lg;
        G2[k]  = __builtin_fmaf(CNEGc * Lg, KCc, KCc);
      }
      // rotate-zero buf[(it-1)%3]: all its readers passed barrier(it); its
      // next adders wait behind barrier(it+1) -> race-free window.
      if (tid < 16) gacc[((it - 1) % 3)*4096 + b*512 + s*16 + tid] = 0.f;
      // f-update, shifted single pass (R5-validated)
      #pragma unroll
      for (int r = 0; r < 8; ++r){
        float sh = Lf[r], sv = 0.f;
        #pragma unroll
        for (int k = 0; k < 8; ++k) sv += fexp2(G2[k] + nK[r*8 + k] - sh);
        float L = sh + flog2(wave_sum(sv));
        Lf[r] = L;
        P[r]  = __builtin_fmaf(CNEGc * L, KCc, laK[r]);
      }
    }
  }

  // ---- epilogue: PI losses from cached tile (P=f30*KC+laK, G2 = g30)
  float ent = 0.f, pix = 0.f, emdf = 0.f, csum[8];
  #pragma unroll
  for (int k = 0; k < 8; ++k) csum[k] = 0.f;
  #pragma unroll
  for (int r = 0; r < 8; ++r){
    float base = P[r] - KCc;
    float An   = fexp2(laK[r] - KCc);
    float fr   = (P[r] - laK[r]) * RKCc;
    float rs = 0.f;
    #pragma unroll
    for (int k = 0; k < 8; ++k){
      float z = base + G2[k] + nK[r*8 + k];
      float p = fexp2(z);
      rs += p; csum[k] += p;
      float q = p + 1e-20f;
      ent = __builtin_fmaf(q * LN2f, flog2(q), ent);
    }
    float RS = wave_sum(rs);
    if (l == 0){
      pix  += fabsf(RS - An);
      emdf += An * (1.f - fexp2(fr * -IRHOL2c));
    }
  }
  // colsums -> atomicAdd into GACC buf0 (zeroed at it=28; adders gated by
  // barrier(29); schedule-consistent with the rotation above)
  #pragma unroll
  for (int k = 0; k < 8; ++k) pmsf[(k*64 + l)*17 + w] = csum[k];
  __syncthreads();
  if (tid < 512){
    float cb = 0.f;
    #pragma unroll
    for (int q = 0; q < 16; ++q) cb += pmsf[tid*17 + q];
    __hip_atomic_fetch_add(&gacc[0*4096 + b*512 + tid], cb,
                           __ATOMIC_RELAXED, __HIP_MEMORY_SCOPE_AGENT);
  }
  bar_sync(cbat + 30, 32);

  // point loss: ONE strip per batch (R4 lesson: guard duplication!)
  float pnt = 0.f;
  if (s == 0 && tid < 512) pnt = fabsf(gacc[b*512 + tid] - 1.f);
  float emdg = 0.f;
  if (s == 0 && w == 0){
    float acc = 0.f;
    #pragma unroll
    for (int k = 0; k < 8; ++k){
      float gm = (G2[k] - KCc) * (1.f / KCc);
      acc += 1.f - fexp2(gm * -IRHOL2c);
    }
    emdg = acc;    // lane covers 8 m's; wave_sum covers all 512
  }

  ent = wave_sum(ent); pix = wave_sum(pix); emdf = wave_sum(emdf);
  pnt = wave_sum(pnt); emdg = wave_sum(emdg);
  if (l == 0){
    red[w*5+0] = ent; red[w*5+1] = pix; red[w*5+2] = emdf; red[w*5+3] = pnt; red[w*5+4] = emdg;
  }
  __syncthreads();
  if (tid == 0){
    float a0=0,a1=0,a2=0,a3=0,a4=0;
    for (int q = 0; q < 16; ++q){
      a0 += red[q*5+0]; a1 += red[q*5+1]; a2 += red[q*5+2]; a3 += red[q*5+3]; a4 += red[q*5+4];
    }
    float* bp = ws + BPARTf + bb*8;
    bp[0]=a0; bp[1]=a1; bp[2]=a2; bp[3]=a3; bp[4]=a4;
  }

  bar_sync(cnt + 1023, 256);   // global barrier (once)

  if (bb == 0){
    float v0=0,v1=0,v2=0,v3=0,v4=0;
    if (tid < 256){
      const float* bp = ws + BPARTf + tid*8;
      v0=bp[0]; v1=bp[1]; v2=bp[2]; v3=bp[3]; v4=bp[4];
    }
    v0=wave_sum(v0); v1=wave_sum(v1); v2=wave_sum(v2); v3=wave_sum(v3); v4=wave_sum(v4);
    if (l == 0){
      red[w*5+0]=v0; red[w*5+1]=v1; red[w*5+2]=v2; red[w*5+3]=v3; red[w*5+4]=v4;
    }
    __syncthreads();
    if (tid == 0){
      float E=0,PX=0,EF=0,PT=0,EG=0;
      for (int q = 0; q < 16; ++q){
        E += red[q*5+0]; PX += red[q*5+1]; EF += red[q*5+2]; PT += red[q*5+3]; EG += red[q*5+4];
      }
      float emd = 0.5f * (EF + EG);
      out[0] = emd + 0.1f * (PX + PT) + 0.01f * (E * (1.f / (4096.f * 512.f)));
    }
  }
}

extern "C" void kernel_launch(void* const* d_in, const int* in_sizes, int n_in,
                              void* d_out, int out_size, void* d_ws, size_t ws_size,
                              hipStream_t stream) {
  const float* A   = (const float*)d_in[0];   // predict_map [8,1,64,64]
  const float* pts = (const float*)d_in[1];   // points [8,512,2]
  float* ws  = (float*)d_ws;
  float* out = (float*)d_out;

  hipMemsetAsync(d_ws, 0, 4096, stream);      // zero barrier counters every call
  k_sink<<<256, 1024, 0, stream>>>(A, pts, ws, out);
}

// Round 7
// 883.423 us; speedup vs baseline: 1.3456x; 1.3456x over previous
//
#include <hip/hip_runtime.h>
#include <math.h>

#define ITERS 30

// ws float offsets. ws[0..1023] ints = flags (memset 0 each launch):
//   cnt[b*32+s] (0..255): per-batch epoch flags, monotonically increasing
//   cnt[512+bb] (512..767): global-final flags
#define PEND0f 1024      // [b][s][m] iter-0 exact LSE partials: 8*32*512
#define GACCf  132096    // [buf3][b][m] atomic sum accumulators: 3*8*512
#define BPARTf 144384    // per-block epilogue partials: 256*8

#define LN2f    0.69314718055994530942f
#define K2c     2.40449173481494868463f   // 1/(0.6*ln2)
#define KCc     144.269504088896340736f   // 100/ln2
#define RKCc    0.0069314718055994530942f // ln2/100
#define CNEGc  -0.0067955605937249540f    // -eps*damping*ln2, damping=0.5/0.51
#define IRHOL2c 2.88539008177792681472f   // 1/(0.5*ln2)

__device__ __forceinline__ float fexp2(float x){ return __builtin_amdgcn_exp2f(x); }
__device__ __forceinline__ float flog2(float x){ return __builtin_amdgcn_logf(x); }
__device__ __forceinline__ float fsq(float x){ return __builtin_amdgcn_sqrtf(x); }

// all cross-block traffic through relaxed agent atomics: executes at the
// coherence point, no L2 writeback/invalidate, immune to XCD placement.
__device__ __forceinline__ void st_atm(float* p, float v){
  __hip_atomic_store(p, v, __ATOMIC_RELAXED, __HIP_MEMORY_SCOPE_AGENT);
}
__device__ __forceinline__ float ld_atm(const float* p){
  return __hip_atomic_load(p, __ATOMIC_RELAXED, __HIP_MEMORY_SCOPE_AGENT);
}

__device__ __forceinline__ float wave_max(float v){
  #pragma unroll
  for (int off = 1; off < 64; off <<= 1) v = fmaxf(v, __shfl_xor(v, off));
  return v;
}
__device__ __forceinline__ float wave_sum(float v){
  #pragma unroll
  for (int off = 1; off < 64; off <<= 1) v += __shfl_xor(v, off);
  return v;
}

// Flag-array barrier. __syncthreads drains every wave's vmcnt (hipcc emits
// s_waitcnt vmcnt(0) before s_barrier), so the flag store is ordered after
// all partial stores/adds reached the coherence point. Poll: wave 0, one
// relaxed atomic load per lane per round — no RMW convoy, no invalidates.
// R3 empirically proved relaxed loads observe remote atomic updates.
__device__ __forceinline__ void bar_flags(int* flags, int idx, int ph){
  __syncthreads();
  if (threadIdx.x == 0)
    __hip_atomic_store(&flags[idx], ph, __ATOMIC_RELAXED, __HIP_MEMORY_SCOPE_AGENT);
  if (threadIdx.x < 32){
    int spins = 0;
    while (__hip_atomic_load(&flags[threadIdx.x], __ATOMIC_RELAXED, __HIP_MEMORY_SCOPE_AGENT) < ph){
      __builtin_amdgcn_s_sleep(2);
      if (++spins > (1 << 18)) break;   // fail visibly, never hang
    }
  }
  __syncthreads();
}

// Block bb: batch b = bb&7, n-strip s = bb>>3 (rows n = s*128 + w*8 + r).
// Lane l, slot k -> m = k*64+l. nK[r][k] = -KC*2^(K2*d(n,m)) in 64 VGPRs.
__global__ __launch_bounds__(1024, 4) void k_sink(const float* __restrict__ A,
                                                  const float* __restrict__ pts,
                                                  float* __restrict__ ws,
                                                  float* __restrict__ out){
  __shared__ float2 pms[512 * 17];
  __shared__ float g_lds[512];
  __shared__ float red[96];
  float* pmsf = (float*)pms;
  const int tid = threadIdx.x, w = tid >> 6, l = tid & 63;
  const int bb = blockIdx.x, b = bb & 7, s = bb >> 3;
  int* cnt   = (int*)ws;
  int* flagB = cnt + b * 32;           // this batch's 32 epoch flags
  float* gacc = ws + GACCf;

  float nK[64], laK[8], P[8], G2[8], Lf[8], shg[8];

  // ---- prologue: cost tile + log-mass; zero this block's GACC slices
  {
    const float2* p2 = (const float2*)(pts + b*1024);
    float px[8], py[8];
    #pragma unroll
    for (int k = 0; k < 8; ++k){
      float2 pv = p2[k*64 + l];
      px[k] = pv.x * (1.f/512.f);
      py[k] = pv.y * (1.f/512.f);
    }
    #pragma unroll
    for (int r = 0; r < 8; ++r){
      int n = s*128 + w*8 + r;
      float xn = (float)((n & 63) + 1) * (1.f/64.f);
      float yn = (float)((n >> 6) + 1) * (1.f/64.f);
      laK[r] = flog2(A[b*4096 + n] + 1e-20f) + KCc;
      P[r]   = laK[r];
      #pragma unroll
      for (int k = 0; k < 8; ++k){
        float dx = xn - px[k], dy = yn - py[k];
        float d2 = __builtin_fmaf(dy, dy, __builtin_fmaf(dx, dx, 1e-12f));
        nK[r*8 + k] = -KCc * fexp2(fsq(d2) * K2c);
      }
    }
    if (tid < 48)                       // zero GACC[0..2][b][s*16..s*16+15]
      st_atm(&gacc[(tid >> 4)*4096 + b*512 + s*16 + (tid & 15)], 0.f);
  }

  // ---- 30 x { g partials -> flag barrier -> combine -> f-update }
  #pragma unroll 1
  for (int it = 0; it < ITERS; ++it){
    if (it == 0){
      // EXACT bootstrap: (M,S) LDS merge, per-column LSE partial to PEND0
      #pragma unroll
      for (int k = 0; k < 8; ++k){
        float y[8], pm = -INFINITY;
        #pragma unroll
        for (int r = 0; r < 8; ++r){ y[r] = P[r] + nK[r*8 + k]; pm = fmaxf(pm, y[r]); }
        float ps = 0.f;
        #pragma unroll
        for (int r = 0; r < 8; ++r) ps += fexp2(y[r] - pm);
        pms[(k*64 + l)*17 + w] = make_float2(pm, ps);
      }
      __syncthreads();
      if (tid < 512){
        float2 v[16]; float M = -INFINITY;
        #pragma unroll
        for (int q = 0; q < 16; ++q){ v[q] = pms[tid*17 + q]; M = fmaxf(M, v[q].x); }
        float S = 0.f;
        #pragma unroll
        for (int q = 0; q < 16; ++q) S += v[q].y * fexp2(v[q].x - M);
        st_atm(&(ws + PEND0f)[(b*32 + s)*512 + tid], M + flog2(S));
      }
      bar_flags(flagB, s, 1);
      // redundant combine of 32 LSE partials (once) -> Lg in g_lds
      {
        int m  = w*32 + (l & 31);
        int s0 = (l >> 5) * 16;
        const float* basep = ws + PEND0f + (b*32 + s0)*512 + m;
        float M = -INFINITY, S = 0.f;
        #pragma unroll
        for (int c = 0; c < 2; ++c){
          float Lr[8], cm = -INFINITY;
          #pragma unroll
          for (int j = 0; j < 8; ++j){ Lr[j] = ld_atm(&basep[(c*8 + j)*512]); cm = fmaxf(cm, Lr[j]); }
          float Mn = fmaxf(M, cm), cs = 0.f;
          #pragma unroll
          for (int j = 0; j < 8; ++j) cs += fexp2(Lr[j] - Mn);
          S = __builtin_fmaf(S, fexp2(M - Mn), cs);
          M = Mn;
        }
        float Mo = __shfl_xor(M, 32), So = __shfl_xor(S, 32);
        float Mn = fmaxf(M, Mo);
        float Sn = __builtin_fmaf(S, fexp2(M - Mn), So * fexp2(Mo - Mn));
        if (!(l & 32)) g_lds[m] = Mn + flog2(Sn);     // Lg (pre-CNEG LSE)
      }
      __syncthreads();
      #pragma unroll
      for (int k = 0; k < 8; ++k){
        float Lg = g_lds[k*64 + l];
        shg[k] = Lg;
        G2[k]  = __builtin_fmaf(CNEGc * Lg, KCc, KCc);
      }
      // f-update, exact wave max (sets Lf)
      #pragma unroll
      for (int r = 0; r < 8; ++r){
        float y[8], cm = -INFINITY;
        #pragma unroll
        for (int k = 0; k < 8; ++k){ y[k] = G2[k] + nK[r*8 + k]; cm = fmaxf(cm, y[k]); }
        float M = wave_max(cm);
        float sv = 0.f;
        #pragma unroll
        for (int k = 0; k < 8; ++k) sv += fexp2(y[k] - M);
        float L = M + flog2(wave_sum(sv));
        Lf[r] = L;
        P[r]  = __builtin_fmaf(CNEGc * L, KCc, laK[r]);
      }
    } else {
      // FAST path: shifted plain sums, relaxed atomicAdd combine (R6-proven math)
      #pragma unroll
      for (int k = 0; k < 8; ++k){
        float sh = shg[k], sv = 0.f;
        #pragma unroll
        for (int r = 0; r < 8; ++r) sv += fexp2(P[r] + nK[r*8 + k] - sh);
        pmsf[(k*64 + l)*17 + w] = sv;
      }
      __syncthreads();
      if (tid < 512){
        float cb = 0.f;
        #pragma unroll
        for (int q = 0; q < 16; ++q) cb += pmsf[tid*17 + q];
        __hip_atomic_fetch_add(&gacc[(it % 3)*4096 + b*512 + tid], cb,
                               __ATOMIC_RELAXED, __HIP_MEMORY_SCOPE_AGENT);
      }
      bar_flags(flagB, s, it + 1);
      // one combined-g read into LDS (512 IF loads, not 8192)
      if (tid < 512) g_lds[tid] = ld_atm(&gacc[(it % 3)*4096 + b*512 + tid]);
      // rotate-zero buf[(it-1)%3]: readers passed barrier(it); next adders
      // gated behind barrier(it+1) -> race-free window.
      if (tid >= 512 && tid < 528)
        st_atm(&gacc[((it - 1) % 3)*4096 + b*512 + s*16 + (tid - 512)], 0.f);
      __syncthreads();
      #pragma unroll
      for (int k = 0; k < 8; ++k){
        float Lg = shg[k] + flog2(g_lds[k*64 + l]);
        shg[k] = Lg;
        G2[k]  = __builtin_fmaf(CNEGc * Lg, KCc, KCc);
      }
      // f-update, shifted single pass (R5-validated)
      #pragma unroll
      for (int r = 0; r < 8; ++r){
        float sh = Lf[r], sv = 0.f;
        #pragma unroll
        for (int k = 0; k < 8; ++k) sv += fexp2(G2[k] + nK[r*8 + k] - sh);
        float L = sh + flog2(wave_sum(sv));
        Lf[r] = L;
        P[r]  = __builtin_fmaf(CNEGc * L, KCc, laK[r]);
      }
    }
  }

  // ---- epilogue: PI losses from cached tile (P=f30*KC+laK, G2 = g30)
  float ent = 0.f, pix = 0.f, emdf = 0.f, csum[8];
  #pragma unroll
  for (int k = 0; k < 8; ++k) csum[k] = 0.f;
  #pragma unroll
  for (int r = 0; r < 8; ++r){
    float base = P[r] - KCc;
    float An   = fexp2(laK[r] - KCc);
    float fr   = (P[r] - laK[r]) * RKCc;
    float rs = 0.f;
    #pragma unroll
    for (int k = 0; k < 8; ++k){
      float z = base + G2[k] + nK[r*8 + k];
      float p = fexp2(z);
      rs += p; csum[k] += p;
      float q = p + 1e-20f;
      ent = __builtin_fmaf(q * LN2f, flog2(q), ent);
    }
    float RS = wave_sum(rs);
    if (l == 0){
      pix  += fabsf(RS - An);
      emdf += An * (1.f - fexp2(fr * -IRHOL2c));
    }
  }
  // colsums -> atomicAdd into GACC buf0 (zeroed at it=28, clean)
  #pragma unroll
  for (int k = 0; k < 8; ++k) pmsf[(k*64 + l)*17 + w] = csum[k];
  __syncthreads();
  if (tid < 512){
    float cb = 0.f;
    #pragma unroll
    for (int q = 0; q < 16; ++q) cb += pmsf[tid*17 + q];
    __hip_atomic_fetch_add(&gacc[0*4096 + b*512 + tid], cb,
                           __ATOMIC_RELAXED, __HIP_MEMORY_SCOPE_AGENT);
  }
  bar_flags(flagB, s, 31);

  // point loss: ONE strip per batch (R4 lesson)
  float pnt = 0.f;
  if (s == 0 && tid < 512) pnt = fabsf(ld_atm(&gacc[b*512 + tid]) - 1.f);
  float emdg = 0.f;
  if (s == 0 && w == 0){
    float acc = 0.f;
    #pragma unroll
    for (int k = 0; k < 8; ++k){
      float gm = (G2[k] - KCc) * (1.f / KCc);
      acc += 1.f - fexp2(gm * -IRHOL2c);
    }
    emdg = acc;
  }

  ent = wave_sum(ent); pix = wave_sum(pix); emdf = wave_sum(emdf);
  pnt = wave_sum(pnt); emdg = wave_sum(emdg);
  if (l == 0){
    red[w*5+0] = ent; red[w*5+1] = pix; red[w*5+2] = emdf; red[w*5+3] = pnt; red[w*5+4] = emdg;
  }
  __syncthreads();
  if (tid == 0){
    float a0=0,a1=0,a2=0,a3=0,a4=0;
    for (int q = 0; q < 16; ++q){
      a0 += red[q*5+0]; a1 += red[q*5+1]; a2 += red[q*5+2]; a3 += red[q*5+3]; a4 += red[q*5+4];
    }
    float* bp = ws + BPARTf + bb*8;
    st_atm(&bp[0], a0); st_atm(&bp[1], a1); st_atm(&bp[2], a2);
    st_atm(&bp[3], a3); st_atm(&bp[4], a4);
  }

  // global final: store own flag (after drain), non-0 blocks exit
  __syncthreads();   // drains BPART stores of tid0
  if (tid == 0)
    __hip_atomic_store(&cnt[512 + bb], 1, __ATOMIC_RELAXED, __HIP_MEMORY_SCOPE_AGENT);
  if (bb != 0) return;

  if (tid < 256){
    int spins = 0;
    while (__hip_atomic_load(&cnt[512 + tid], __ATOMIC_RELAXED, __HIP_MEMORY_SCOPE_AGENT) < 1){
      __builtin_amdgcn_s_sleep(2);
      if (++spins > (1 << 18)) break;
    }
  }
  __syncthreads();

  {
    float v0=0,v1=0,v2=0,v3=0,v4=0;
    if (tid < 256){
      const float* bp = ws + BPARTf + tid*8;
      v0=ld_atm(&bp[0]); v1=ld_atm(&bp[1]); v2=ld_atm(&bp[2]);
      v3=ld_atm(&bp[3]); v4=ld_atm(&bp[4]);
    }
    v0=wave_sum(v0); v1=wave_sum(v1); v2=wave_sum(v2); v3=wave_sum(v3); v4=wave_sum(v4);
    if (l == 0){
      red[w*5+0]=v0; red[w*5+1]=v1; red[w*5+2]=v2; red[w*5+3]=v3; red[w*5+4]=v4;
    }
    __syncthreads();
    if (tid == 0){
      float E=0,PX=0,EF=0,PT=0,EG=0;
      for (int q = 0; q < 16; ++q){
        E += red[q*5+0]; PX += red[q*5+1]; EF += red[q*5+2]; PT += red[q*5+3]; EG += red[q*5+4];
      }
      float emd = 0.5f * (EF + EG);
      out[0] = emd + 0.1f * (PX + PT) + 0.01f * (E * (1.f / (4096.f * 512.f)));
    }
  }
}

extern "C" void kernel_launch(void* const* d_in, const int* in_sizes, int n_in,
                              void* d_out, int out_size, void* d_ws, size_t ws_size,
                              hipStream_t stream) {
  const float* A   = (const float*)d_in[0];   // predict_map [8,1,64,64]
  const float* pts = (const float*)d_in[1];   // points [8,512,2]
  float* ws  = (float*)d_ws;
  float* out = (float*)d_out;

  hipMemsetAsync(d_ws, 0, 4096, stream);      // zero all flags every call
  k_sink<<<256, 1024, 0, stream>>>(A, pts, ws, out);
}